// Round 9
// baseline (201.911 us; speedup 1.0000x reference)
//
#include <hip/hip_runtime.h>
#include <math.h>

// ---------------------------------------------------------------------------
// Grok5PhiCore: out = proj( softmax(QK^T*scale + phi_bias) V ).
// B=2, L=2048, D=1024, H=16, Dh=64.
//
// v8: attn rewritten REGISTER-DIRECT (no LDS, no barriers in hot loop):
//  - each wave owns 64 q x ALL 2048 j -> no cross-wave combine at all.
//  - K/V fragments read straight from global (L2-resident; bh->XCD swizzle
//    keeps each XCD's working set at 4 bh = 2 MB < 4 MB L2). Sector-aligned:
//    K frag = 16 rows x 64B sector; V frag = one b128 from the j-permuted
//    d-major vb layout (v7). 2-phase register double-buffer; compiler
//    pipelines with fine-grained vmcnt (no barrier drains).
//  - S^T register-P trick, static-max softmax, ones-MFMA row sums as before.
//  - GEMMs/prep unchanged from v7b.
//
// Workspace (48 MB, fp16):
//   xb    [4096][1024]   8 MB   x cast
//   wqkvT [3072][1024]   6 MB   w_qkv transposed
//   wpT   [1024][1024]   2 MB   w_proj transposed
//   qb    [32][2048][64] 8 MB   Q per head, PRE-SCALED by 0.125*log2e
//   kb    [32][2048][64] 8 MB   K per head
//   vb    [32][64][2048] 8 MB   V^T per head, j-permuted (written by gemm)
//   ctx   [4096][1024]   8 MB   attn output
// ---------------------------------------------------------------------------

typedef _Float16 f16;
typedef _Float16 f16x4 __attribute__((ext_vector_type(4)));
typedef _Float16 f16x8 __attribute__((ext_vector_type(8)));
typedef float f32x4 __attribute__((ext_vector_type(4)));

#define MFMA32(a, b, c) __builtin_amdgcn_mfma_f32_16x16x32_f16(a, b, c, 0, 0, 0)

static constexpr int Bsz = 2, Lseq = 2048, Dm = 1024, H = 16, Dh = 64;
static constexpr int Mtot = Bsz * Lseq;        // 4096
static constexpr int NQKV = 3 * Dm;            // 3072
static constexpr float PHI_F = 1.61803398874989484820f;
static constexpr float LOG2E = 1.44269504088896f;
static constexpr float QS = 0.125f * LOG2E;    // folded into stored q
static constexpr float CSTEP32 = 0.77708763999663514f;  // fract(32*phi)

// pack two floats -> two f16 (RTZ)
__device__ __forceinline__ void pk2(float a, float b, f16* d) {
  auto v = __builtin_amdgcn_cvt_pkrtz(a, b);  // __fp16 ext_vector(2)
  d[0] = (f16)v[0];
  d[1] = (f16)v[1];
}

// async 16B global -> LDS (lds dest = wave-uniform base + lane*16)
__device__ __forceinline__ void load16_to_lds(const f16* g, f16* l) {
  __builtin_amdgcn_global_load_lds(
      (const __attribute__((address_space(1))) unsigned int*)g,
      (__attribute__((address_space(3))) unsigned int*)l, 16, 0, 0);
}

// ---------------- fused prep: cast x, transpose w_qkv, transpose w_proj ----
__global__ __launch_bounds__(256) void prep_kernel(
    const float* __restrict__ x, const float* __restrict__ wqkv,
    const float* __restrict__ wproj, f16* __restrict__ xb,
    f16* __restrict__ wqkvT, f16* __restrict__ wpT) {
  __shared__ float tile[32][33];
  int bid = blockIdx.x, tid = threadIdx.x;
  if (bid < 4096) {  // cast 4 elems/thread
    int i = bid * 1024 + tid * 4;
    float4 v = *reinterpret_cast<const float4*>(x + i);
    f16 t[4] = {(f16)v.x, (f16)v.y, (f16)v.z, (f16)v.w};
    *reinterpret_cast<uint2*>(xb + i) = *reinterpret_cast<uint2*>(t);
    return;
  }
  const float* in;
  f16* out;
  int K, N, n0, k0;
  if (bid < 4096 + 3072) {
    int b2 = bid - 4096;
    in = wqkv; out = wqkvT; K = Dm; N = NQKV;
    n0 = (b2 % 96) * 32; k0 = (b2 / 96) * 32;
  } else {
    int b2 = bid - 7168;
    in = wproj; out = wpT; K = Dm; N = Dm;
    n0 = (b2 & 31) * 32; k0 = (b2 >> 5) * 32;
  }
  int tx = tid & 31, ty = tid >> 5;  // 32 x 8
#pragma unroll
  for (int r = 0; r < 32; r += 8)
    tile[ty + r][tx] = in[(size_t)(k0 + ty + r) * N + n0 + tx];
  __syncthreads();
#pragma unroll
  for (int r = 0; r < 32; r += 8)
    out[(size_t)(n0 + ty + r) * K + k0 + tx] = (f16)tile[tx][ty + r];
}

// ---------------- GEMM: C[M,N] = A[M,K] * Bt[N,K]^T  (fp16, fp32 acc) ------
// m97-style: global_load_lds(16B) staging, BK=64, unpadded LDS with
// global-side XOR chunk swizzle. MODE 0: 128x128 tile, QKV epilogue
// (v written directly in permuted d-major). MODE 1: 64x128, fp32 out + bias.
template <int MODE>
__global__ __launch_bounds__(256) void gemm_f16(
    const f16* __restrict__ A, const f16* __restrict__ Bt,
    int M, int N, int K,
    f16* __restrict__ qb, f16* __restrict__ kb, f16* __restrict__ vb,
    float* __restrict__ out, const float* __restrict__ bias) {
  constexpr int BM = (MODE == 0) ? 128 : 64;
  constexpr int MI = BM / 32;
  constexpr int AI = BM / 32;
  __shared__ f16 As[BM * 64];
  __shared__ f16 Bs[128 * 64];

  int tid = threadIdx.x;
  int wave = tid >> 6, lane = tid & 63;
  int quad = lane >> 4, l16 = lane & 15;
  int wm = (wave >> 1) * (MI * 16), wn = (wave & 1) * 64;

  int lid = blockIdx.x;
  int xcd = lid & 7, t = lid >> 3;
  int m0, n0;
  if (MODE == 0) {
    int mg = xcd >> 1, ng = xcd & 1;
    m0 = (mg * 8 + t / 12) * 128;
    n0 = (ng * 12 + t % 12) * 128;
  } else {
    m0 = (xcd * 8 + (t >> 3)) * 64;
    n0 = (t & 7) * 128;
  }

  const int gu = (lane & 7) ^ (lane >> 3);
  const f16* gA[AI];
  f16* lA[AI];
#pragma unroll
  for (int i = 0; i < AI; i++) {
    int it = wave * AI + i;
    gA[i] = A + (size_t)(m0 + it * 8 + (lane >> 3)) * K + gu * 8;
    lA[i] = As + it * 512;
  }
  const f16* gB[4];
  f16* lB[4];
#pragma unroll
  for (int i = 0; i < 4; i++) {
    int it = wave * 4 + i;
    gB[i] = Bt + (size_t)(n0 + it * 8 + (lane >> 3)) * K + gu * 8;
    lB[i] = Bs + it * 512;
  }

  f32x4 acc[MI][4] = {};

  for (int k0 = 0; k0 < K; k0 += 64) {
#pragma unroll
    for (int i = 0; i < AI; i++) load16_to_lds(gA[i] + k0, lA[i]);
#pragma unroll
    for (int i = 0; i < 4; i++) load16_to_lds(gB[i] + k0, lB[i]);
    __syncthreads();
#pragma unroll
    for (int s = 0; s < 2; s++) {
      f16x8 a[MI], b[4];
#pragma unroll
      for (int i = 0; i < MI; i++) {
        int row = wm + i * 16 + l16;
        a[i] = *reinterpret_cast<const f16x8*>(
            As + row * 64 + (((s * 4 + quad) ^ (l16 & 7)) * 8));
      }
#pragma unroll
      for (int j = 0; j < 4; j++) {
        int row = wn + j * 16 + l16;
        b[j] = *reinterpret_cast<const f16x8*>(
            Bs + row * 64 + (((s * 4 + quad) ^ (l16 & 7)) * 8));
      }
#pragma unroll
      for (int i = 0; i < MI; i++)
#pragma unroll
        for (int j = 0; j < 4; j++)
          acc[i][j] = MFMA32(a[i], b[j], acc[i][j]);
    }
    __syncthreads();
  }

  if (MODE == 1) {
#pragma unroll
    for (int i = 0; i < MI; i++)
#pragma unroll
      for (int j = 0; j < 4; j++) {
        int n = n0 + wn + j * 16 + l16;
#pragma unroll
        for (int r = 0; r < 4; r++) {
          int m = m0 + wm + i * 16 + quad * 4 + r;
          out[(size_t)m * N + n] = acc[i][j][r] + bias[n];
        }
      }
    return;
  }
  int ty = n0 >> 10;  // wave-uniform: 0=q 1=k 2=v
  if (ty < 2) {
    f16* dst = (ty == 0) ? qb : kb;
    float sc = (ty == 0) ? QS : 1.0f;
#pragma unroll
    for (int i = 0; i < MI; i++)
#pragma unroll
      for (int j = 0; j < 4; j++) {
        int n = n0 + wn + j * 16 + l16;
        int h = (n & 1023) >> 6, dh = n & 63;
#pragma unroll
        for (int r = 0; r < 4; r++) {
          int m = m0 + wm + i * 16 + quad * 4 + r;
          int b = m >> 11, l = m & 2047;
          dst[(((size_t)(b * H + h)) * Lseq + l) * Dh + dh] =
              (f16)(acc[i][j][r] * sc);
        }
      }
  } else {
    // v: permuted d-major vb[bh][dh][64grp*64 + c*8 + e0 + r], b64 stores
#pragma unroll
    for (int i = 0; i < MI; i++) {
      int mb = m0 + wm + i * 16 + quad * 4;
      int b = mb >> 11, l = mb & 2047;
      int L0 = l & ~63, lg = l & 63;
      int c = ((lg >> 5) << 2) | ((lg >> 2) & 3);
      int e0 = ((lg >> 4) & 1) * 4;
      int off = L0 + c * 8 + e0;
#pragma unroll
      for (int j = 0; j < 4; j++) {
        int n = n0 + wn + j * 16 + l16;
        int h = (n & 1023) >> 6, dh = n & 63;
        f16x4 v;
        pk2(acc[i][j][0], acc[i][j][1], (f16*)&v);
        pk2(acc[i][j][2], acc[i][j][3], ((f16*)&v) + 2);
        *reinterpret_cast<uint2*>(
            vb + ((size_t)(b * H + h) * Dh + dh) * Lseq + off) =
            *reinterpret_cast<uint2*>(&v);
      }
    }
  }
}

// ---------------- flash attention v8: register-direct, no LDS, no barriers -
// grid: 256 blocks x 256 threads. Each wave: 64 q (4 sets of 16) x all j.
// bh->XCD swizzle: bid%8 == bh%8 so each XCD's K/V working set is 4 bh (2MB).
__global__ __launch_bounds__(256, 1) void attn_kernel(
    const f16* __restrict__ qb,   // [BH][L][64], pre-scaled by QS
    const f16* __restrict__ kb,   // [BH][L][64]
    const f16* __restrict__ vb,   // [BH][64][L], j-permuted
    f16* __restrict__ ctx) {      // [B*L][1024]
  int bid = blockIdx.x;
  int xcd = bid & 7, rr = bid >> 3;
  int qblk = rr & 7, bgrp = rr >> 3;
  int bh = bgrp * 8 + xcd;
  int tid = threadIdx.x, wave = tid >> 6, lane = tid & 63;
  int quad = lane >> 4, l16 = lane & 15;
  int qw = qblk * 256 + wave * 64;  // this wave's 64-q base

  const f16* Kbh = kb + (size_t)bh * Lseq * Dh;
  const f16* Vbh = vb + (size_t)bh * Dh * Lseq;

  // Q B-frags: 4 sets x 2 halves of d
  f16x8 qfrag[4][2];
  float pq[4];
#pragma unroll
  for (int set = 0; set < 4; set++) {
    int q = qw + set * 16 + l16;
    const f16* Qrow = qb + ((size_t)bh * Lseq + q) * Dh;
    qfrag[set][0] = *reinterpret_cast<const f16x8*>(Qrow + quad * 8);
    qfrag[set][1] = *reinterpret_cast<const f16x8*>(Qrow + 32 + quad * 8);
    pq[set] = fmodf((float)q * PHI_F, 1.0f);
  }

  // phi positions for this lane's j-slots (phase p covers j in [32p,32p+32))
  float pk[2][4];
#pragma unroll
  for (int jb = 0; jb < 2; jb++)
#pragma unroll
    for (int r = 0; r < 4; r++)
      pk[jb][r] = fmodf((float)(jb * 16 + quad * 4 + r) * PHI_F, 1.0f);

  // fragment base pointers
  const f16* pK[2][2];  // [jb][s], + p*2048 per phase
#pragma unroll
  for (int jb = 0; jb < 2; jb++)
#pragma unroll
    for (int s = 0; s < 2; s++)
      pK[jb][s] = Kbh + (size_t)(jb * 16 + l16) * Dh + s * 32 + quad * 8;
  const f16* pV[4];     // [dblk], + p*32 per phase
#pragma unroll
  for (int d = 0; d < 4; d++)
    pV[d] = Vbh + (size_t)(d * 16 + l16) * Lseq + quad * 8;

  const f16 one = (f16)1.0f;
  const f16x8 ones8 = {one, one, one, one, one, one, one, one};

  f32x4 acc_o[4][4] = {};  // [set][dblk]  O^T: row d=quad*4+r, col q=l16
  f32x4 acc_l[4] = {};     // row sums via ones-MFMA

  f16x8 ka[2][2], vfa[4], kc[2][2], vfc[4];

  auto loadA = [&](int p) {
#pragma unroll
    for (int jb = 0; jb < 2; jb++)
#pragma unroll
      for (int s = 0; s < 2; s++)
        ka[jb][s] = *reinterpret_cast<const f16x8*>(pK[jb][s] + p * 2048);
#pragma unroll
    for (int d = 0; d < 4; d++)
      vfa[d] = *reinterpret_cast<const f16x8*>(pV[d] + p * 32);
  };
  auto loadC = [&](int p) {
#pragma unroll
    for (int jb = 0; jb < 2; jb++)
#pragma unroll
      for (int s = 0; s < 2; s++)
        kc[jb][s] = *reinterpret_cast<const f16x8*>(pK[jb][s] + p * 2048);
#pragma unroll
    for (int d = 0; d < 4; d++)
      vfc[d] = *reinterpret_cast<const f16x8*>(pV[d] + p * 32);
  };

  auto compute = [&](f16x8 (&kf)[2][2], f16x8 (&vf)[4]) {
    // S^T = K * Q^T  (per set: 16 q cols; 32 j rows via 2 jb)
    f32x4 accs[4][2] = {};
#pragma unroll
    for (int s = 0; s < 2; s++)
#pragma unroll
      for (int jb = 0; jb < 2; jb++)
#pragma unroll
        for (int set = 0; set < 4; set++)
          accs[set][jb] = MFMA32(kf[jb][s], qfrag[set][s], accs[set][jb]);
    // p = exp2(s2 - |pq-pk|*log2e); pack K=32 PV B-frags (permuted k-order)
    f16x8 pf8[4];
#pragma unroll
    for (int set = 0; set < 4; set++) {
#pragma unroll
      for (int jb = 0; jb < 2; jb++) {
        float p[4];
#pragma unroll
        for (int r = 0; r < 4; r++) {
          float d = pq[set] - pk[jb][r];
          float arg = fmaf(-LOG2E, fabsf(d), accs[set][jb][r]);
          p[r] = __builtin_amdgcn_exp2f(arg);
        }
        pk2(p[0], p[1], ((f16*)&pf8[set]) + jb * 4);
        pk2(p[2], p[3], ((f16*)&pf8[set]) + jb * 4 + 2);
      }
      acc_l[set] = MFMA32(ones8, pf8[set], acc_l[set]);
    }
#pragma unroll
    for (int jb = 0; jb < 2; jb++)
#pragma unroll
      for (int r = 0; r < 4; r++)
        pk[jb][r] = __builtin_amdgcn_fractf(pk[jb][r] + CSTEP32);
    // O^T += V^T * P^T
#pragma unroll
    for (int dblk = 0; dblk < 4; dblk++)
#pragma unroll
      for (int set = 0; set < 4; set++)
        acc_o[set][dblk] = MFMA32(vf[dblk], pf8[set], acc_o[set][dblk]);
  };

  loadA(0);
  for (int p = 0; p < 64; p += 2) {
    loadC(p + 1);
    compute(ka, vfa);
    if (p + 2 < 64) loadA(p + 2);
    compute(kc, vfc);
  }

  // epilogue: each wave owns its q fully — no combine
  int b = bh >> 4, h = bh & 15;
#pragma unroll
  for (int set = 0; set < 4; set++) {
    float inv = 1.0f / acc_l[set][0];
    int q = qw + set * 16 + l16;
    f16* crow = ctx + (size_t)(b * Lseq + q) * Dm + h * 64;
#pragma unroll
    for (int dblk = 0; dblk < 4; dblk++) {
      f16x4 o;
      pk2(acc_o[set][dblk][0] * inv, acc_o[set][dblk][1] * inv, (f16*)&o);
      pk2(acc_o[set][dblk][2] * inv, acc_o[set][dblk][3] * inv, ((f16*)&o) + 2);
      *reinterpret_cast<uint2*>(crow + dblk * 16 + quad * 4) =
          *reinterpret_cast<uint2*>(&o);
    }
  }
}

// ---------------------------------------------------------------------------
extern "C" void kernel_launch(void* const* d_in, const int* in_sizes, int n_in,
                              void* d_out, int out_size, void* d_ws, size_t ws_size,
                              hipStream_t stream) {
  const float* x      = (const float*)d_in[0];  // [2,2048,1024]
  const float* w_qkv  = (const float*)d_in[1];  // [1024,3072]
  const float* w_proj = (const float*)d_in[2];  // [1024,1024]
  const float* b_proj = (const float*)d_in[3];  // [1024]
  float* out = (float*)d_out;                   // [2,2048,1024]

  f16* xb    = (f16*)d_ws;                       // 4096*1024
  f16* wqkvT = xb + (size_t)Mtot * Dm;           // 3072*1024
  f16* wpT   = wqkvT + (size_t)NQKV * Dm;        // 1024*1024
  f16* qb    = wpT + (size_t)Dm * Dm;            // 32*2048*64
  f16* kb    = qb + (size_t)Bsz * H * Lseq * Dh;
  f16* vb    = kb + (size_t)Bsz * H * Lseq * Dh;
  f16* ctx   = vb + (size_t)Bsz * H * Lseq * Dh; // 4096*1024

  // fused prep: cast x + transpose both weights
  prep_kernel<<<8192, 256, 0, stream>>>(x, w_qkv, w_proj, xb, wqkvT, wpT);

  // QKV GEMM -> q (scaled), k l-major; v directly permuted d-major
  gemm_f16<0><<<768, 256, 0, stream>>>(
      xb, wqkvT, Mtot, NQKV, Dm, qb, kb, vb, nullptr, nullptr);

  // attention (register-direct, 256 blocks, bh->XCD swizzled)
  attn_kernel<<<256, 256, 0, stream>>>(qb, kb, vb, ctx);

  // proj GEMM: [4096,1024] x [1024,1024] + bias (64x128 tiles)
  gemm_f16<1><<<512, 256, 0, stream>>>(
      ctx, wpT, Mtot, Dm, Dm, nullptr, nullptr, nullptr, out, b_proj);
}